// Round 1
// 148.782 us; speedup vs baseline: 1.1780x; 1.1780x over previous
//
#include <hip/hip_runtime.h>
#include <math.h>

#define BS_     64
#define NUM_KP_ 17
#define A_      8400
#define GRID_   80          // IMAGE_SIZE / STRIDES[0] = 640/8
#define NCH_    (3 * NUM_KP_)   // 51
#define NROWS_  (BS_ * NUM_KP_)             // 1088
#define NCONF_  ((float)(BS_ * NUM_KP_ * A_))  // 9139200

// One block per (batch, keypoint) conf row.
// Writes a fully-scaled per-row partial to ws[row] (no atomics, no memset:
// every ws slot the final kernel reads is unconditionally overwritten here).
//
// log1p(-c) == log(1-c) for c in [0,1): Sterbenz => 1-c exact for c>=0.5;
// for c<0.5 the subtraction error is <=2^-24 rel. __logf = v_log_f32 + mul,
// ~5 instrs vs ~35 for libm log1pf. Loss magnitude ~1e6 (xy term dominates),
// so the <=1e-6-level conf perturbation is far below any tolerance.
__global__ __launch_bounds__(256) void yolo_kploss_main(
    const float* __restrict__ out,   // (BS, 51, 8400)
    const float* __restrict__ gt,    // (BS, 17, 2)
    const int*   __restrict__ visv,  // (BS, 17)
    float*       __restrict__ ws)    // ws[row] = per-row scaled partial
{
    const int row = blockIdx.x;              // 0 .. 1087
    const int b   = row / NUM_KP_;
    const int k   = row - b * NUM_KP_;
    const int tid = threadIdx.x;

    const float* conf_row = out + ((size_t)b * NCH_ + 3 * k + 2) * A_;

    float conf_part = 0.0f;

    // A_ = 8400 = 2100 float4, contiguous & 16B-aligned.
    const float4* c4 = (const float4*)conf_row;
    #pragma unroll 4
    for (int i = tid; i < A_ / 4; i += 256) {
        float4 v = c4[i];
        conf_part += fmaxf(__logf(1.0f - v.x), -100.0f);
        conf_part += fmaxf(__logf(1.0f - v.y), -100.0f);
        conf_part += fmaxf(__logf(1.0f - v.z), -100.0f);
        conf_part += fmaxf(__logf(1.0f - v.w), -100.0f);
    }

    float extra = 0.0f;   // xy/BS for this row (+0 conf adj goes into conf_part)
    if (tid == 0) {
        const float gx = gt[(b * NUM_KP_ + k) * 2 + 0];
        const float gy = gt[(b * NUM_KP_ + k) * 2 + 1];
        const int   vv = visv[b * NUM_KP_ + k];
        if (vv == 1) {
            const int bx  = (int)floorf(gx * 0.125f);
            const int by  = (int)floorf(gy * 0.125f);
            const int idx = by * GRID_ + bx;        // < 6400 < 8400
            const float xg = out[((size_t)b * NCH_ + 3 * k + 0) * A_ + idx];
            const float yg = out[((size_t)b * NCH_ + 3 * k + 1) * A_ + idx];
            const float c  = conf_row[idx];
            extra = ((xg - gx) * (xg - gx) + (yg - gy) * (yg - gy)) * (1.0f / BS_);
            const float logp   = fmaxf(__logf(c),        -100.0f);  // log(0) = -inf -> clamped
            const float log1mp = fmaxf(__logf(1.0f - c), -100.0f);
            conf_part += (logp - log1mp);   // masked position: logp replaces log1mp
        }
    }

    // Block reduce conf_part: wave64 shuffle, then LDS across the 4 waves.
    #pragma unroll
    for (int off = 32; off > 0; off >>= 1)
        conf_part += __shfl_down(conf_part, off, 64);

    __shared__ float s[4];
    const int wave = tid >> 6;
    const int lane = tid & 63;
    if (lane == 0) s[wave] = conf_part;
    __syncthreads();

    if (tid == 0) {
        const float total = s[0] + s[1] + s[2] + s[3];
        ws[row] = extra - total * (1.0f / NCONF_);
    }
}

// Reduce the 1088 per-row partials to the scalar loss.
__global__ __launch_bounds__(256) void yolo_kploss_final(
    const float* __restrict__ ws, float* __restrict__ outp)
{
    const int tid = threadIdx.x;
    float acc = 0.0f;
    for (int i = tid; i < NROWS_; i += 256) acc += ws[i];   // 4-5 each
    #pragma unroll
    for (int off = 32; off > 0; off >>= 1)
        acc += __shfl_down(acc, off, 64);
    __shared__ float s[4];
    if ((tid & 63) == 0) s[tid >> 6] = acc;
    __syncthreads();
    if (tid == 0) outp[0] = s[0] + s[1] + s[2] + s[3];
}

extern "C" void kernel_launch(void* const* d_in, const int* in_sizes, int n_in,
                              void* d_out, int out_size, void* d_ws, size_t ws_size,
                              hipStream_t stream) {
    const float* out_t = (const float*)d_in[0];   // (64, 51, 8400) fp32
    // d_in[1] = target, unused by the reference math
    const float* gt    = (const float*)d_in[2];   // (64, 17, 2) fp32
    const int*   vis   = (const int*)d_in[3];     // (64, 17) int32

    float* ws = (float*)d_ws;

    yolo_kploss_main<<<NROWS_, 256, 0, stream>>>(out_t, gt, vis, ws);
    yolo_kploss_final<<<1, 256, 0, stream>>>(ws, (float*)d_out);
}